// Round 8
// baseline (718.404 us; speedup 1.0000x reference)
//
#include <hip/hip_runtime.h>
#include <math.h>

#define B_ 4
#define N_ 50000
#define E_ 800000
#define IN_ 128
#define H_ 4
#define D_ 32
#define HD_ 128
#define M_ (B_*N_)   // 200000 rows total
#define GT_ (M_/64)  // 3125 row-tiles of 64

constexpr float GAT_SLOPE = 0.2f;
constexpr float ACT_SLOPE = 0.01f;
constexpr float BN_EPS = 1e-5f;

typedef __attribute__((ext_vector_type(8))) short bf16x8;
typedef __attribute__((ext_vector_type(4))) float f32x4;

// XOR-swizzle (T2): spread row-major column reads across banks; bits 4-6 only.
#define SWZ(r, b) ((b) ^ (((r) & 7) << 4))

__device__ __forceinline__ unsigned short f2bf(float x) {   // RNE
    unsigned u = __float_as_uint(x);
    return (unsigned short)((u + 0x7FFFu + ((u >> 16) & 1u)) >> 16);
}
__device__ __forceinline__ float bf2f(unsigned short h) {
    return __uint_as_float(((unsigned)h) << 16);
}
__device__ __forceinline__ float bflo(unsigned u) { return __uint_as_float(u << 16); }
__device__ __forceinline__ float bfhi(unsigned u) { return __uint_as_float(u & 0xFFFF0000u); }

// ---- MFMA GEMM: featb[row, c] = bf16( sum_k xx[row,k]*W[k,c] ), rows=B*N, K=C=128.
// NON-persistent: one block per 64-row tile. Stage W^T + X as bf16 (swizzled),
// one barrier, compute, write. W re-read per block is L2/L3-resident (R6 PMC:
// gemm was 9.7% HBM). 48KB LDS -> 3 blocks/CU.
__global__ __launch_bounds__(256) void gemm_kernel(const float* __restrict__ xx,
                                                   const float* __restrict__ W,
                                                   unsigned short* __restrict__ featb) {
    __shared__ __align__(16) char WtL[128 * 256];  // 32 KB: W^T bf16 [c][k], swizzled
    __shared__ __align__(16) char XsL[64 * 256];   // 16 KB: X  bf16 [r][k], swizzled
    const int tid = threadIdx.x;
    const int lane = tid & 63;
    const int wv = tid >> 6;          // wave 0..3
    const int lr = lane & 15;
    const int lq = lane >> 4;         // 0..3
    const int arow = wv * 16 + lr;    // A row within 64-row tile
    const long row0 = (long)blockIdx.x * 64;

    // stage W^T: read W[k][c] f32 coalesced, write bf16 at [c][k] (swizzled)
    for (int i = tid; i < IN_ * HD_ / 4; i += 256) {
        int k = i >> 5;
        int c0 = (i & 31) << 2;
        float4 v = ((const float4*)W)[i];
        unsigned short p[4] = {f2bf(v.x), f2bf(v.y), f2bf(v.z), f2bf(v.w)};
#pragma unroll
        for (int j = 0; j < 4; ++j) {
            int c = c0 + j;
            *(unsigned short*)(WtL + SWZ(c, c * 256 + k * 2)) = p[j];
        }
    }
    // stage X tile: bf16, swizzled
    for (int i = tid; i < 64 * IN_ / 4; i += 256) {
        int r = i >> 5;
        int c0 = (i & 31) << 2;
        float4 v = ((const float4*)(xx + row0 * IN_))[i];
        ushort4 p;
        p.x = f2bf(v.x); p.y = f2bf(v.y); p.z = f2bf(v.z); p.w = f2bf(v.w);
        *(ushort4*)(XsL + SWZ(r, r * 256 + c0 * 2)) = p;
    }
    __syncthreads();

    f32x4 acc[8] = {};
#pragma unroll
    for (int ks = 0; ks < 4; ++ks) {
        bf16x8 a = *(const bf16x8*)(XsL + SWZ(arow, arow * 256 + ks * 64 + lq * 16));
#pragma unroll
        for (int nt = 0; nt < 8; ++nt) {
            int br = nt * 16 + lr;
            bf16x8 b = *(const bf16x8*)(WtL + SWZ(br, br * 256 + ks * 64 + lq * 16));
            acc[nt] = __builtin_amdgcn_mfma_f32_16x16x32_bf16(a, b, acc[nt], 0, 0, 0);
        }
    }

    // C/D: col = lane&15, row = (lane>>4)*4 + r  (m89/m91-verified)
    unsigned short* fout = featb + (row0 + wv * 16 + lq * 4) * HD_ + lr;
#pragma unroll
    for (int nt = 0; nt < 8; ++nt)
#pragma unroll
        for (int r = 0; r < 4; ++r)
            fout[r * HD_ + nt * 16] = f2bf(acc[nt][r]);
}

// ---- el/er: per-node per-head dot of feat(bf16) with attn vectors ----
__global__ __launch_bounds__(256) void elr_kernel(const unsigned short* __restrict__ featb,
                                                  const float* __restrict__ al,
                                                  const float* __restrict__ ar,
                                                  float* __restrict__ el,
                                                  float* __restrict__ er) {
    const int tid = threadIdx.x;
    const int c = tid & 127;
    const int h = c >> 5, d = c & 31;
    const int half = tid >> 7;
    for (long rp = blockIdx.x; rp < M_ / 2; rp += gridDim.x) {
        long row = rp * 2 + half;
        float f = bf2f(featb[row * HD_ + c]);
        float pl = f * al[c];
        float pr = f * ar[c];
        for (int o = 16; o; o >>= 1) {
            pl += __shfl_down(pl, o, 32);
            pr += __shfl_down(pr, o, 32);
        }
        if (d == 0) {
            el[row * H_ + h] = pl;
            er[row * H_ + h] = pr;
        }
    }
}

// ---- CSR build step 1: in-degree histogram over dst ----
__global__ __launch_bounds__(256) void hist_kernel(const int* __restrict__ dst,
                                                   int* __restrict__ counts) {
    for (int e = blockIdx.x * 256 + threadIdx.x; e < E_; e += gridDim.x * 256)
        atomicAdd(&counts[dst[e]], 1);
}

// ---- CSR build step 2: exclusive scan of counts -> offsets (+cursor copy) ----
__global__ __launch_bounds__(1024) void scan_kernel(const int* __restrict__ counts,
                                                    int* __restrict__ offsets,
                                                    int* __restrict__ cursor) {
    __shared__ int part[1024];
    const int tid = threadIdx.x;
    const int CH = (N_ + 1023) / 1024;   // 49
    const int base = tid * CH;
    int s = 0;
    for (int i = 0; i < CH; ++i) {
        int idx = base + i;
        if (idx < N_) s += counts[idx];
    }
    part[tid] = s;
    __syncthreads();
    for (int off = 1; off < 1024; off <<= 1) {
        int v = (tid >= off) ? part[tid - off] : 0;
        __syncthreads();
        part[tid] += v;
        __syncthreads();
    }
    int run = (tid == 0) ? 0 : part[tid - 1];
    for (int i = 0; i < CH; ++i) {
        int idx = base + i;
        if (idx < N_) {
            offsets[idx] = run;
            cursor[idx] = run;
            run += counts[idx];
        }
    }
    if (tid == 0) offsets[N_] = part[1023];   // == E_
}

// ---- CSR build step 3: scatter src ids into dst-sorted order ----
__global__ __launch_bounds__(256) void scatter_kernel(const int* __restrict__ src,
                                                      const int* __restrict__ dst,
                                                      int* __restrict__ cursor,
                                                      int* __restrict__ srcs) {
    for (int e = blockIdx.x * 256 + threadIdx.x; e < E_; e += gridDim.x * 256) {
        int pos = atomicAdd(&cursor[dst[e]], 1);
        srcs[pos] = src[e];
    }
}

// ---- per-(b,node) softmax + aggregation: ONE WAVE per (b,n).
// Lane t owns channels {2t, 2t+1} (head h = t>>4): gathers are dword loads.
// Per 16-edge tile, lane l computes w for (edge l&15, head l>>4); w and the
// precomputed byte offset are shared via shfl (no LDS, no barriers).
// blockIdx->(b,n) swizzled so XCD k serves only batch k/2 (L2 affinity).
__global__ __launch_bounds__(64) void aggregate_kernel(const int* __restrict__ offsets,
                                                       const int* __restrict__ srcs,
                                                       const float* __restrict__ el,
                                                       const float* __restrict__ er,
                                                       const unsigned short* __restrict__ featb,
                                                       float* __restrict__ out) {
    const int t = threadIdx.x;        // 0..63
    const int h = t >> 4;             // head of channels 2t,2t+1
    const int hb = t & 48;            // head-group base lane
    const int t4 = 4 * t;             // byte offset of dword within feat row
    const unsigned g = blockIdx.x;    // 200000 blocks, %8==0
    const int xcd = (int)(g & 7u);
    const int b = xcd >> 1;           // 2 XCDs per batch
    const int n = (int)((g >> 3) * 2 + (xcd & 1));
    const long bbase = (long)b * N_;
    const int beg = offsets[n], end = offsets[n + 1];

    const float ern = er[(bbase + n) * H_ + h];
    const char* fbase = (const char*)(featb + bbase * HD_);
    const int j16 = t & 15;

    float acc0 = 0.f, acc1 = 0.f, dsum = 0.f;
    for (int c0 = beg; c0 < end; c0 += 16) {
        const int cnt = min(16, end - c0);
        float w = 0.f;
        int off = 0;
        if (j16 < cnt) {
            int s = srcs[c0 + j16];
            off = s << 8;   // s * 256 bytes (128 bf16 per row)
            float ev = el[(bbase + s) * H_ + h] + ern;
            ev = ev >= 0.f ? ev : GAT_SLOPE * ev;
            w = __expf(ev);   // no max-shift: scores O(+-6), alpha shift-invariant
        }
        dsum += w;
        int j = 0;
        for (; j + 3 < cnt; j += 4) {
            int o0 = __shfl(off, j);
            int o1 = __shfl(off, j + 1);
            int o2 = __shfl(off, j + 2);
            int o3 = __shfl(off, j + 3);
            float w0 = __shfl(w, hb | j);
            float w1 = __shfl(w, hb | (j + 1));
            float w2 = __shfl(w, hb | (j + 2));
            float w3 = __shfl(w, hb | (j + 3));
            unsigned u0 = *(const unsigned*)(fbase + o0 + t4);
            unsigned u1 = *(const unsigned*)(fbase + o1 + t4);
            unsigned u2 = *(const unsigned*)(fbase + o2 + t4);
            unsigned u3 = *(const unsigned*)(fbase + o3 + t4);
            acc0 = fmaf(w0, bflo(u0), acc0); acc1 = fmaf(w0, bfhi(u0), acc1);
            acc0 = fmaf(w1, bflo(u1), acc0); acc1 = fmaf(w1, bfhi(u1), acc1);
            acc0 = fmaf(w2, bflo(u2), acc0); acc1 = fmaf(w2, bfhi(u2), acc1);
            acc0 = fmaf(w3, bflo(u3), acc0); acc1 = fmaf(w3, bfhi(u3), acc1);
        }
        for (; j < cnt; ++j) {
            int o0 = __shfl(off, j);
            float w0 = __shfl(w, hb | j);
            unsigned u0 = *(const unsigned*)(fbase + o0 + t4);
            acc0 = fmaf(w0, bflo(u0), acc0);
            acc1 = fmaf(w0, bfhi(u0), acc1);
        }
    }
#pragma unroll
    for (int o = 8; o; o >>= 1) dsum += __shfl_xor(dsum, o, 64);
    const float inv = 1.0f / fmaxf(dsum, 1e-9f);
    float2 res = make_float2(acc0 * inv, acc1 * inv);
    *(float2*)&out[((bbase + n) * HD_) + 2 * t] = res;
}

// ---- per-channel sum/sumsq for BN (read-only) ----
__global__ __launch_bounds__(256) void stats_kernel(const float* __restrict__ out,
                                                    float* __restrict__ chsum) {
    const int tid = threadIdx.x;
    const int c = tid & 127;
    const int half = tid >> 7;
    float s = 0.f, s2 = 0.f;
    for (long rp = blockIdx.x; rp < M_ / 2; rp += gridDim.x) {
        long row = rp * 2 + half;
        float v = out[row * HD_ + c];
        s += v;
        s2 += v * v;
    }
    __shared__ float red[512];
    red[tid] = s; red[256 + tid] = s2;
    __syncthreads();
    if (tid < 128) {
        s = red[tid] + red[tid + 128];
        s2 = red[256 + tid] + red[256 + tid + 128];
        atomicAdd(&chsum[c], s);
        atomicAdd(&chsum[128 + c], s2);
    }
}

// ---- BN params: scale/shift per channel ----
__global__ void params_kernel(const float* __restrict__ chsum,
                              const float* __restrict__ gamma,
                              const float* __restrict__ beta,
                              float* __restrict__ ss) {
    int c = threadIdx.x;  // 128 threads
    float mean = chsum[c] / (float)M_;
    float var = chsum[128 + c] / (float)M_ - mean * mean;
    float rstd = rsqrtf(var + BN_EPS);
    float sc = rstd * gamma[c];
    ss[c] = sc;
    ss[128 + c] = beta[c] - mean * sc;
}

// ---- normalize + final leaky relu, in place on d_out ----
__global__ __launch_bounds__(256) void norm_kernel(float* __restrict__ out,
                                                   const float* __restrict__ ss) {
    __shared__ float s_sc[128], s_sh[128];
    if (threadIdx.x < 128) {
        s_sc[threadIdx.x] = ss[threadIdx.x];
        s_sh[threadIdx.x] = ss[128 + threadIdx.x];
    }
    __syncthreads();
    const long total4 = (long)M_ * HD_ / 4;
    for (long i = (long)blockIdx.x * 256 + threadIdx.x; i < total4;
         i += (long)gridDim.x * 256) {
        float4 v = ((float4*)out)[i];
        int c = (int)((i & 31) << 2);   // (i*4) % 128
        float4 r;
        r.x = v.x * s_sc[c + 0] + s_sh[c + 0];
        r.y = v.y * s_sc[c + 1] + s_sh[c + 1];
        r.z = v.z * s_sc[c + 2] + s_sh[c + 2];
        r.w = v.w * s_sc[c + 3] + s_sh[c + 3];
        r.x = r.x >= 0.f ? r.x : ACT_SLOPE * r.x;
        r.y = r.y >= 0.f ? r.y : ACT_SLOPE * r.y;
        r.z = r.z >= 0.f ? r.z : ACT_SLOPE * r.z;
        r.w = r.w >= 0.f ? r.w : ACT_SLOPE * r.w;
        ((float4*)out)[i] = r;
    }
}

extern "C" void kernel_launch(void* const* d_in, const int* in_sizes, int n_in,
                              void* d_out, int out_size, void* d_ws, size_t ws_size,
                              hipStream_t stream) {
    const float* xx    = (const float*)d_in[0];
    const float* W     = (const float*)d_in[1];
    const float* al    = (const float*)d_in[2];
    const float* ar    = (const float*)d_in[3];
    const float* gamma = (const float*)d_in[4];
    const float* beta  = (const float*)d_in[5];
    const int*   src   = (const int*)d_in[6];
    const int*   dst   = (const int*)d_in[7];
    float* out = (float*)d_out;

    char* ws = (char*)d_ws;
    unsigned short* featb = (unsigned short*)ws; ws += (size_t)M_ * HD_ * 2;  // 51.2 MB
    float* el      = (float*)ws;  ws += (size_t)M_ * H_ * 4;    // 3.2 MB
    float* er      = (float*)ws;  ws += (size_t)M_ * H_ * 4;
    int*   counts  = (int*)ws;    ws += (size_t)N_ * 4;
    int*   offsets = (int*)ws;    ws += (size_t)(N_ + 1) * 4;
    int*   cursor  = (int*)ws;    ws += (size_t)N_ * 4;
    int*   srcs    = (int*)ws;    ws += (size_t)E_ * 4;         // 3.2 MB
    float* chsum   = (float*)ws;  ws += 256 * 4;
    float* ss      = (float*)ws;  ws += 256 * 4;

    hipMemsetAsync(counts, 0, (size_t)N_ * 4, stream);
    hipMemsetAsync(chsum, 0, 256 * 4, stream);

    gemm_kernel<<<GT_, 256, 0, stream>>>(xx, W, featb);
    elr_kernel<<<4096, 256, 0, stream>>>(featb, al, ar, el, er);
    hist_kernel<<<2048, 256, 0, stream>>>(dst, counts);
    scan_kernel<<<1, 1024, 0, stream>>>(counts, offsets, cursor);
    scatter_kernel<<<2048, 256, 0, stream>>>(src, dst, cursor, srcs);
    aggregate_kernel<<<M_, 64, 0, stream>>>(offsets, srcs, el, er, featb, out);
    stats_kernel<<<2048, 256, 0, stream>>>(out, chsum);
    params_kernel<<<1, 128, 0, stream>>>(chsum, gamma, beta, ss);
    norm_kernel<<<4096, 256, 0, stream>>>(out, ss);
}